// Round 8
// baseline (624.570 us; speedup 1.0000x reference)
//
#include <hip/hip_runtime.h>
#include <hip/hip_bf16.h>

#define NL 32768L

typedef __bf16 bf16x8 __attribute__((ext_vector_type(8)));
typedef float f32x16 __attribute__((ext_vector_type(16)));
typedef float f32x3 __attribute__((ext_vector_type(3)));
typedef float f32x4v __attribute__((ext_vector_type(4)));

struct LastT  { static constexpr bool v = true;  };
struct NLastT { static constexpr bool v = false; };

__device__ __forceinline__ unsigned short f2bf(float f) {
  unsigned int u = __float_as_uint(f);
  u += 0x7FFFu + ((u >> 16) & 1u);   // round-to-nearest-even
  return (unsigned short)(u >> 16);
}

__device__ __forceinline__ float frcp(float x) {
  float r;
  asm("v_rcp_f32 %0, %1" : "=v"(r) : "v"(x));
  return r;
}

__device__ __forceinline__ void gload16(const void* g, void* l) {
  __builtin_amdgcn_global_load_lds((const __attribute__((address_space(1))) void*)g,
                                   (__attribute__((address_space(3))) void*)l, 16, 0, 0);
}

template <int N>
__device__ __forceinline__ void vmwait() {
  if constexpr (N == 0) asm volatile("s_waitcnt vmcnt(0)" ::: "memory");
  else if constexpr (N == 5) asm volatile("s_waitcnt vmcnt(5)" ::: "memory");
  else if constexpr (N == 6) asm volatile("s_waitcnt vmcnt(6)" ::: "memory");
  else if constexpr (N == 7) asm volatile("s_waitcnt vmcnt(7)" ::: "memory");
  else static_assert(N == 0, "unsupported vmcnt");
}

// ---- combined prep: x -> bf16 d-major planes, weights -> transposed bf16 ----
__global__ void prep_kernel(const float* __restrict__ x,
                            const float* __restrict__ w1_0, const float* __restrict__ w1_1,
                            const float* __restrict__ w1_2, const float* __restrict__ w2_0,
                            const float* __restrict__ w2_1, const float* __restrict__ w2_2,
                            unsigned short* __restrict__ Xp, unsigned short* __restrict__ W) {
  long i = (long)blockIdx.x * blockDim.x + threadIdx.x;
  if (i < NL * 512) {
    long n = i >> 9, u = i & 511;
    Xp[i] = f2bf(x[n * 1920 + u]);
  } else if (i < NL * 768) {
    long j = i - NL * 512;
    long n = j >> 8, u = j & 255;
    const float* s = x + n * 1920 + 512 + u * 3;
    unsigned short* d = Xp + NL * 512 + n * 256 + u;
    d[0]        = f2bf(s[0]);
    d[NL * 256] = f2bf(s[1]);
    d[NL * 512] = f2bf(s[2]);
  } else if (i < NL * 896) {
    long j = i - NL * 768;
    long n = j >> 7, u = j & 127;
    const float* s = x + n * 1920 + 1280 + u * 5;
    unsigned short* d = Xp + NL * 1280 + n * 128 + u;
#pragma unroll
    for (int k = 0; k < 5; ++k) d[k * NL * 128] = f2bf(s[k]);
  } else {
    long j = i - NL * 896;
    if (j < 524288) {            // w1_0: K=512, C=1024
      int c = (int)(j >> 9), r = (int)(j & 511);
      W[j] = f2bf(w1_0[(long)r * 1024 + c]);
    } else if (j < 655360) {     // w1_1: K=256, C=512
      long t = j - 524288; int c = (int)(t >> 8), r = (int)(t & 255);
      W[j] = f2bf(w1_1[(long)r * 512 + c]);
    } else if (j < 688128) {     // w1_2: K=128, C=256
      long t = j - 655360; int c = (int)(t >> 7), r = (int)(t & 127);
      W[j] = f2bf(w1_2[(long)r * 256 + c]);
    } else if (j < 1212416) {    // w2_0: K=1024, C=512
      long t = j - 688128; int c = (int)(t >> 10), r = (int)(t & 1023);
      W[j] = f2bf(w2_0[(long)r * 512 + c]);
    } else if (j < 1343488) {    // w2_1: K=512, C=256
      long t = j - 1212416; int c = (int)(t >> 9), r = (int)(t & 511);
      W[j] = f2bf(w2_1[(long)r * 256 + c]);
    } else if (j < 1376256) {    // w2_2: K=256, C=128
      long t = j - 1343488; int c = (int)(t >> 8), r = (int)(t & 255);
      W[j] = f2bf(w2_2[(long)r * 128 + c]);
    }
  }
}

// ---- persistent-tile GEMM core --------------------------------------------
// 256 thr, 4 waves 2x2, per-wave RM=BM/2 x RN=BN/2, 32x32x16 MFMA, BK=32.
// Each block owns MT consecutive m-tiles at one n0: prologue paid once,
// epilogue(i) overlaps in-flight prefetch of tile i+1 (counted vmcnt).
// NBUF=3: counted-vmcnt depth-2 (vmwait<ITER>).  NBUF=2: dbuf drain.
// Bank swizzle: 16B slot ^= (row>>1)&3 on BOTH gload source and ds_read.
// MODE 0: normact across P planes -> bf16 planes.  MODE 1: f32 interleaved out.
template <int P, int BM, int BN, int K, int NN, int MODE, int NBUF, int MT>
__device__ __forceinline__ void gemm_core(
    unsigned short* sm, int b,
    const unsigned short* __restrict__ Ap, long planeA,
    const unsigned short* __restrict__ Wt,
    void* __restrict__ outp, long planeOut, int outOff, float sc) {
  constexpr int BK = 32;
  constexpr int RM = BM / 2, RN = BN / 2;
  constexpr int FM = RM / 32, FN = RN / 32;
  constexpr int CHA = P * BM * 4, CHB = BN * 4, TCH = CHA + CHB;  // 16B chunks
  constexpr int ITER = TCH / 256;
  static_assert(TCH % 256 == 0, "uniform staging");
  constexpr int ABUF = P * BM * BK;            // elems
  constexpr int BUFE = ABUF + BN * BK;
  constexpr int NT = K / BK;
  constexpr int NX = NN / BN;
  constexpr int MG = 32768 / BM / MT;
  constexpr int NWG = MG * NX;
  constexpr int S = MT * NT;
  static_assert(NWG % 8 == 0, "XCD swizzle");

  const int tid = threadIdx.x;
  const int lane = tid & 63, wv = tid >> 6;
  const int wr = wv >> 1, wc = wv & 1;
  const int ln31 = lane & 31, kh = lane >> 5;

  const int wg = (b & 7) * (NWG / 8) + (b >> 3);
  const int mg = wg / NX;
  const long baseM = (long)mg * MT * BM;
  const int n0 = (wg % NX) * BN;

  f32x16 acc[P][FM][FN];
#pragma unroll
  for (int p = 0; p < P; ++p)
#pragma unroll
    for (int a = 0; a < FM; ++a)
#pragma unroll
      for (int c = 0; c < FN; ++c) acc[p][a][c] = (f32x16)0.f;

  auto stage = [&](unsigned short* buf, int tile, int t) {
#pragma unroll
    for (int it = 0; it < ITER; ++it) {
      int c = it * 256 + tid;
      if constexpr (true) {}
      if ((it + 1) * 256 <= CHA) {         // A chunk (folds per unrolled it)
        int p = c / (BM * 4);
        int cp = c - p * (BM * 4);
        int row = cp >> 2, sl = cp & 3;
        int slp = sl ^ ((row >> 1) & 3);
        gload16(Ap + (long)p * planeA + (baseM + tile * BM + row) * K + t * BK + slp * 8,
                buf + c * 8);
      } else {                             // B chunk
        int cb = c - CHA;
        int row = cb >> 2, sl = cb & 3;
        int slp = sl ^ ((row >> 1) & 3);
        gload16(Wt + (long)(n0 + row) * K + t * BK + slp * 8, buf + ABUF + cb * 8);
      }
    }
  };

  auto compute = [&](const unsigned short* buf) {
#pragma unroll
    for (int ks = 0; ks < 2; ++ks) {
      bf16x8 bv[FN];
#pragma unroll
      for (int fn = 0; fn < FN; ++fn) {
        int row = wc * RN + fn * 32 + ln31;
        int s = (ks * 2 + kh) ^ ((row >> 1) & 3);
        bv[fn] = *(const bf16x8*)(buf + ABUF + row * BK + s * 8);
      }
      bf16x8 av[P][FM];
#pragma unroll
      for (int p = 0; p < P; ++p)
#pragma unroll
        for (int fm = 0; fm < FM; ++fm) {
          int row = wr * RM + fm * 32 + ln31;
          int s = (ks * 2 + kh) ^ ((row >> 1) & 3);
          av[p][fm] = *(const bf16x8*)(buf + p * BM * BK + row * BK + s * 8);
        }
      __builtin_amdgcn_s_setprio(1);
#pragma unroll
      for (int p = 0; p < P; ++p)
#pragma unroll
        for (int fm = 0; fm < FM; ++fm)
#pragma unroll
          for (int fn = 0; fn < FN; ++fn)
            acc[p][fm][fn] = __builtin_amdgcn_mfma_f32_32x32x16_bf16(
                av[p][fm], bv[fn], acc[p][fm][fn], 0, 0, 0);
      __builtin_amdgcn_s_setprio(0);
    }
  };

  auto epilogue = [&](int i) {
    const long mt0 = baseM + (long)i * BM;
    if constexpr (MODE == 0) {
      __hip_bfloat16* H = (__hip_bfloat16*)outp;
#pragma unroll
      for (int fm = 0; fm < FM; ++fm)
#pragma unroll
        for (int fn = 0; fn < FN; ++fn)
#pragma unroll
          for (int reg = 0; reg < 16; ++reg) {
            long row = mt0 + wr * RM + fm * 32 + (reg & 3) + 8 * (reg >> 2) + 4 * kh;
            int col = n0 + wc * RN + fn * 32 + ln31;
            float vs[P];
            float n2 = 0.f;
#pragma unroll
            for (int p = 0; p < P; ++p) {
              float v = acc[p][fm][fn][reg] * sc;
              vs[p] = v;
              n2 += v * v;
            }
            float nm = (P == 1) ? fabsf(vs[0]) : sqrtf(n2);
            float sg = frcp(1.f + __expf(-nm));   // silu(n)/n == sigmoid(n)
#pragma unroll
            for (int p = 0; p < P; ++p)
              H[p * planeOut + row * NN + col] = __float2bfloat16(vs[p] * sg);
          }
    } else {
      float* O = (float*)outp;
#pragma unroll
      for (int fm = 0; fm < FM; ++fm)
#pragma unroll
        for (int fn = 0; fn < FN; ++fn)
#pragma unroll
          for (int reg = 0; reg < 16; ++reg) {
            long row = mt0 + wr * RM + fm * 32 + (reg & 3) + 8 * (reg >> 2) + 4 * kh;
            int col = n0 + wc * RN + fn * 32 + ln31;
            float* base = O + row * 1920 + outOff + (long)col * P;
            if constexpr (P == 1) {
              base[0] = acc[0][fm][fn][reg] * sc;
            } else if constexpr (P == 3) {
              f32x3 v3;
#pragma unroll
              for (int p = 0; p < 3; ++p) v3[p] = acc[p][fm][fn][reg] * sc;
              *(f32x3*)base = v3;
            } else {
              f32x4v v4;
#pragma unroll
              for (int p = 0; p < 4; ++p) v4[p] = acc[p][fm][fn][reg] * sc;
              *(f32x4v*)base = v4;
              base[4] = acc[4][fm][fn][reg] * sc;
            }
          }
    }
#pragma unroll
    for (int p = 0; p < P; ++p)
#pragma unroll
      for (int a = 0; a < FM; ++a)
#pragma unroll
        for (int c = 0; c < FN; ++c) acc[p][a][c] = (f32x16)0.f;
  };

  unsigned short* b0 = sm;
  unsigned short* b1 = sm + BUFE;

  if constexpr (NBUF == 3) {
    unsigned short* b2 = sm + 2 * BUFE;
    stage(b0, 0, 0);
    stage(b1, 0, 1);                     // NT >= 8 in all NBUF==3 branches
    auto run_tile = [&](int i, auto lastc) {
#pragma unroll
      for (int t = 0; t < NT; ++t) {
        if (decltype(lastc)::v && t == NT - 1) vmwait<0>();
        else vmwait<ITER>();             // substep-s chunks landed; s+1 in flight
        __builtin_amdgcn_s_barrier();
        asm volatile("" ::: "memory");
        if (!decltype(lastc)::v || t < NT - 2) {
          stage(b2, i + (t + 2) / NT, (t + 2) & (NT - 1));
        }
        compute(b0);
        unsigned short* tmp = b0; b0 = b1; b1 = b2; b2 = tmp;
      }
    };
#pragma unroll 1
    for (int i = 0; i < MT - 1; ++i) {
      run_tile(i, NLastT{});
      epilogue(i);                       // overlaps tile i+1 prefetch in flight
    }
    run_tile(MT - 1, LastT{});
    epilogue(MT - 1);
  } else {
    stage(b0, 0, 0);
    vmwait<0>();
    __builtin_amdgcn_s_barrier();
    asm volatile("" ::: "memory");
#pragma unroll 1
    for (int i = 0; i < MT; ++i) {
#pragma unroll
      for (int t = 0; t < NT; ++t) {
        if (i * NT + t + 1 < S) stage(b1, i + (t + 1) / NT, (t + 1) & (NT - 1));
        compute(b0);
        vmwait<0>();
        __builtin_amdgcn_s_barrier();
        asm volatile("" ::: "memory");
        unsigned short* tmp = b0; b0 = b1; b1 = tmp;
      }
      epilogue(i);
    }
  }
}

// ---- fat dispatches (256 thr, uniform 73728 B LDS -> 2 blocks/CU) ----------
__global__ __launch_bounds__(256, 2) void fat1_kernel(
    const unsigned short* __restrict__ Xp, const unsigned short* __restrict__ W,
    unsigned short* __restrict__ Hp) {
  extern __shared__ unsigned short sm[];
  int b = blockIdx.x;
  if (b < 512) {         // l0: 128x256, K=512, MT=2, counted 3-buf
    gemm_core<1, 128, 256, 512, 1024, 0, 3, 2>(sm, b, Xp, 0, W, Hp, 0, 0, 0.04419417382f);
  } else if (b < 1536) { // l1: P=3, 64x128, K=256, MT=2, counted 3-buf
    gemm_core<3, 64, 128, 256, 512, 0, 3, 2>(sm, b - 512, Xp + NL * 512, NL * 256, W + 524288,
                                             Hp + NL * 1024, NL * 512, 0, 0.0625f);
  } else {               // l2: P=5, 64x128, K=128, MT=2, dbuf
    gemm_core<5, 64, 128, 128, 256, 0, 2, 2>(sm, b - 1536, Xp + NL * 1280, NL * 128, W + 655360,
                                             Hp + NL * 2560, NL * 256, 0, 0.08838834765f);
  }
}

__global__ __launch_bounds__(256, 2) void fat2_kernel(
    const unsigned short* __restrict__ Hp, const unsigned short* __restrict__ W,
    float* __restrict__ out) {
  extern __shared__ unsigned short sm[];
  int b = blockIdx.x;
  if (b < 256) {        // l0: 128x256, K=1024, MT=2
    gemm_core<1, 128, 256, 1024, 512, 1, 3, 2>(sm, b, Hp, 0, W + 688128, out, 0, 0, 0.03125f);
  } else if (b < 768) { // l1: P=3, 64x128, K=512, MT=2
    gemm_core<3, 64, 128, 512, 256, 1, 3, 2>(sm, b - 256, Hp + NL * 1024, NL * 512, W + 1212416,
                                             out, 0, 512, 0.04419417382f);
  } else {              // l2: P=5, 64x128, K=256, MT=2, dbuf
    gemm_core<5, 64, 128, 256, 128, 1, 2, 2>(sm, b - 768, Hp + NL * 2560, NL * 256, W + 1343488,
                                             out, 0, 1280, 0.0625f);
  }
}

extern "C" void kernel_launch(void* const* d_in, const int* in_sizes, int n_in,
                              void* d_out, int out_size, void* d_ws, size_t ws_size,
                              hipStream_t stream) {
  const float* x = (const float*)d_in[0];
  const float* w1_0 = (const float*)d_in[1];
  const float* w1_1 = (const float*)d_in[2];
  const float* w1_2 = (const float*)d_in[3];
  const float* w2_0 = (const float*)d_in[4];
  const float* w2_1 = (const float*)d_in[5];
  const float* w2_2 = (const float*)d_in[6];
  float* out = (float*)d_out;

  unsigned short* Xp = (unsigned short*)d_ws;      // N*1920 bf16
  unsigned short* Hp = Xp + NL * 1920;             // N*3840 bf16
  unsigned short* W  = Hp + NL * 3840;             // 1376256 bf16 (all Wt blocks)

  {
    long total = NL * 896 + 1376256;
    prep_kernel<<<dim3((unsigned)((total + 255) / 256)), dim3(256), 0, stream>>>(
        x, w1_0, w1_1, w1_2, w2_0, w2_1, w2_2, Xp, W);
  }

  fat1_kernel<<<2048, 256, 73728, stream>>>(Xp, W, Hp);
  fat2_kernel<<<1024, 256, 73728, stream>>>(Hp, W, out);
}

// Round 9
// 408.765 us; speedup vs baseline: 1.5279x; 1.5279x over previous
//
#include <hip/hip_runtime.h>
#include <hip/hip_bf16.h>

#define NL 32768L

typedef __bf16 bf16x8 __attribute__((ext_vector_type(8)));
typedef float f32x16 __attribute__((ext_vector_type(16)));
typedef float f32x3 __attribute__((ext_vector_type(3)));
typedef float f32x4v __attribute__((ext_vector_type(4)));

__device__ __forceinline__ unsigned short f2bf(float f) {
  unsigned int u = __float_as_uint(f);
  u += 0x7FFFu + ((u >> 16) & 1u);   // round-to-nearest-even
  return (unsigned short)(u >> 16);
}

__device__ __forceinline__ float frcp(float x) {
  float r;
  asm("v_rcp_f32 %0, %1" : "=v"(r) : "v"(x));
  return r;
}

__device__ __forceinline__ void gload16(const void* g, void* l) {
  __builtin_amdgcn_global_load_lds((const __attribute__((address_space(1))) void*)g,
                                   (__attribute__((address_space(3))) void*)l, 16, 0, 0);
}

__device__ __forceinline__ void vmwait0() {
  asm volatile("s_waitcnt vmcnt(0)" ::: "memory");
}

// ---- combined prep: x -> bf16 d-major planes, weights -> transposed bf16 ----
__global__ void prep_kernel(const float* __restrict__ x,
                            const float* __restrict__ w1_0, const float* __restrict__ w1_1,
                            const float* __restrict__ w1_2, const float* __restrict__ w2_0,
                            const float* __restrict__ w2_1, const float* __restrict__ w2_2,
                            unsigned short* __restrict__ Xp, unsigned short* __restrict__ W) {
  long i = (long)blockIdx.x * blockDim.x + threadIdx.x;
  if (i < NL * 512) {
    long n = i >> 9, u = i & 511;
    Xp[i] = f2bf(x[n * 1920 + u]);
  } else if (i < NL * 768) {
    long j = i - NL * 512;
    long n = j >> 8, u = j & 255;
    const float* s = x + n * 1920 + 512 + u * 3;
    unsigned short* d = Xp + NL * 512 + n * 256 + u;
    d[0]        = f2bf(s[0]);
    d[NL * 256] = f2bf(s[1]);
    d[NL * 512] = f2bf(s[2]);
  } else if (i < NL * 896) {
    long j = i - NL * 768;
    long n = j >> 7, u = j & 127;
    const float* s = x + n * 1920 + 1280 + u * 5;
    unsigned short* d = Xp + NL * 1280 + n * 128 + u;
#pragma unroll
    for (int k = 0; k < 5; ++k) d[k * NL * 128] = f2bf(s[k]);
  } else {
    long j = i - NL * 896;
    if (j < 524288) {            // w1_0: K=512, C=1024
      int c = (int)(j >> 9), r = (int)(j & 511);
      W[j] = f2bf(w1_0[(long)r * 1024 + c]);
    } else if (j < 655360) {     // w1_1: K=256, C=512
      long t = j - 524288; int c = (int)(t >> 8), r = (int)(t & 255);
      W[j] = f2bf(w1_1[(long)r * 512 + c]);
    } else if (j < 688128) {     // w1_2: K=128, C=256
      long t = j - 655360; int c = (int)(t >> 7), r = (int)(t & 127);
      W[j] = f2bf(w1_2[(long)r * 256 + c]);
    } else if (j < 1212416) {    // w2_0: K=1024, C=512
      long t = j - 688128; int c = (int)(t >> 10), r = (int)(t & 1023);
      W[j] = f2bf(w2_0[(long)r * 512 + c]);
    } else if (j < 1343488) {    // w2_1: K=512, C=256
      long t = j - 1212416; int c = (int)(t >> 9), r = (int)(t & 511);
      W[j] = f2bf(w2_1[(long)r * 256 + c]);
    } else if (j < 1376256) {    // w2_2: K=256, C=128
      long t = j - 1343488; int c = (int)(t >> 8), r = (int)(t & 255);
      W[j] = f2bf(w2_2[(long)r * 128 + c]);
    }
  }
}

// ---- GEMM core: 256 thr, 4 waves 2x2, 32x32x16 MFMA, BK=32, dbuf -----------
// Small tiles -> 48KB LDS max -> 3 blocks/CU (block-level TLP hides stalls,
// m97/m114 pattern). Schedule: stage(t+1) BEFORE compute(t); one vmcnt(0)
// + s_barrier per substep after compute (loads get full compute phase).
// Bank swizzle: 16B slot ^= (row>>1)&3 on BOTH gload source and ds_read.
// MODE 0: normact across P planes -> bf16 planes.  MODE 1: f32 interleaved out.
template <int P, int BM, int BN, int K, int NN, int MODE>
__device__ __forceinline__ void gemm_core(
    unsigned short* sm, int b,
    const unsigned short* __restrict__ Ap, long planeA,
    const unsigned short* __restrict__ Wt,
    void* __restrict__ outp, long planeOut, int outOff, float sc) {
  constexpr int BK = 32;
  constexpr int RM = BM / 2, RN = BN / 2;
  constexpr int FM = RM / 32, FN = RN / 32;
  constexpr int CHA = P * BM * 4, CHB = BN * 4, TCH = CHA + CHB;  // 16B chunks
  constexpr int ITER = TCH / 256;
  static_assert(TCH % 256 == 0 && CHA % 256 == 0, "uniform staging");
  constexpr int ABUF = P * BM * BK;            // elems
  constexpr int BUFE = ABUF + BN * BK;
  constexpr int NT = K / BK;
  constexpr int NX = NN / BN;
  constexpr int NWG = (32768 / BM) * NX;
  static_assert(NWG % 8 == 0, "XCD swizzle");

  const int tid = threadIdx.x;
  const int lane = tid & 63, wv = tid >> 6;
  const int wr = wv >> 1, wc = wv & 1;
  const int ln31 = lane & 31, kh = lane >> 5;

  const int wg = (b & 7) * (NWG / 8) + (b >> 3);   // bijective XCD swizzle
  const long m0 = (long)(wg / NX) * BM;
  const int n0 = (wg % NX) * BN;

  f32x16 acc[P][FM][FN];
#pragma unroll
  for (int p = 0; p < P; ++p)
#pragma unroll
    for (int a = 0; a < FM; ++a)
#pragma unroll
      for (int c = 0; c < FN; ++c) acc[p][a][c] = (f32x16)0.f;

  auto stage = [&](unsigned short* buf, int t) {
#pragma unroll
    for (int it = 0; it < ITER; ++it) {
      int c = it * 256 + tid;
      if ((it + 1) * 256 <= CHA) {         // compile-time split per unrolled it
        int p = c / (BM * 4);
        int cp = c - p * (BM * 4);
        int row = cp >> 2, sl = cp & 3;
        int slp = sl ^ ((row >> 1) & 3);
        gload16(Ap + (long)p * planeA + (m0 + row) * K + t * BK + slp * 8, buf + c * 8);
      } else {
        int cb = c - CHA;
        int row = cb >> 2, sl = cb & 3;
        int slp = sl ^ ((row >> 1) & 3);
        gload16(Wt + (long)(n0 + row) * K + t * BK + slp * 8, buf + ABUF + cb * 8);
      }
    }
  };

  auto compute = [&](const unsigned short* buf) {
#pragma unroll
    for (int ks = 0; ks < 2; ++ks) {
      bf16x8 bv[FN];
#pragma unroll
      for (int fn = 0; fn < FN; ++fn) {
        int row = wc * RN + fn * 32 + ln31;
        int s = (ks * 2 + kh) ^ ((row >> 1) & 3);
        bv[fn] = *(const bf16x8*)(buf + ABUF + row * BK + s * 8);
      }
      bf16x8 av[P][FM];
#pragma unroll
      for (int p = 0; p < P; ++p)
#pragma unroll
        for (int fm = 0; fm < FM; ++fm) {
          int row = wr * RM + fm * 32 + ln31;
          int s = (ks * 2 + kh) ^ ((row >> 1) & 3);
          av[p][fm] = *(const bf16x8*)(buf + p * BM * BK + row * BK + s * 8);
        }
      __builtin_amdgcn_s_setprio(1);
#pragma unroll
      for (int p = 0; p < P; ++p)
#pragma unroll
        for (int fm = 0; fm < FM; ++fm)
#pragma unroll
          for (int fn = 0; fn < FN; ++fn)
            acc[p][fm][fn] = __builtin_amdgcn_mfma_f32_32x32x16_bf16(
                av[p][fm], bv[fn], acc[p][fm][fn], 0, 0, 0);
      __builtin_amdgcn_s_setprio(0);
    }
  };

  stage(sm, 0);
  vmwait0();
  __builtin_amdgcn_s_barrier();
  asm volatile("" ::: "memory");
#pragma unroll
  for (int t = 0; t < NT; ++t) {
    if (t + 1 < NT) stage(sm + ((t + 1) & 1) * BUFE, t + 1);
    compute(sm + (t & 1) * BUFE);
    if (t + 1 < NT) {
      vmwait0();
      __builtin_amdgcn_s_barrier();
      asm volatile("" ::: "memory");
    }
  }

  if constexpr (MODE == 0) {
    __hip_bfloat16* H = (__hip_bfloat16*)outp;
#pragma unroll
    for (int fm = 0; fm < FM; ++fm)
#pragma unroll
      for (int fn = 0; fn < FN; ++fn)
#pragma unroll
        for (int reg = 0; reg < 16; ++reg) {
          long row = m0 + wr * RM + fm * 32 + (reg & 3) + 8 * (reg >> 2) + 4 * kh;
          int col = n0 + wc * RN + fn * 32 + ln31;
          float vs[P];
          float n2 = 0.f;
#pragma unroll
          for (int p = 0; p < P; ++p) {
            float v = acc[p][fm][fn][reg] * sc;
            vs[p] = v;
            n2 += v * v;
          }
          float nm = (P == 1) ? fabsf(vs[0]) : sqrtf(n2);
          float sg = frcp(1.f + __expf(-nm));   // silu(n)/n == sigmoid(n)
#pragma unroll
          for (int p = 0; p < P; ++p)
            H[p * planeOut + row * NN + col] = __float2bfloat16(vs[p] * sg);
        }
  } else {
    float* O = (float*)outp;
#pragma unroll
    for (int fm = 0; fm < FM; ++fm)
#pragma unroll
      for (int fn = 0; fn < FN; ++fn)
#pragma unroll
        for (int reg = 0; reg < 16; ++reg) {
          long row = m0 + wr * RM + fm * 32 + (reg & 3) + 8 * (reg >> 2) + 4 * kh;
          int col = n0 + wc * RN + fn * 32 + ln31;
          float* base = O + row * 1920 + outOff + (long)col * P;
          if constexpr (P == 1) {
            base[0] = acc[0][fm][fn][reg] * sc;
          } else if constexpr (P == 3) {
            f32x3 v3;
#pragma unroll
            for (int p = 0; p < 3; ++p) v3[p] = acc[p][fm][fn][reg] * sc;
            *(f32x3*)base = v3;
          } else {
            f32x4v v4;
#pragma unroll
            for (int p = 0; p < 4; ++p) v4[p] = acc[p][fm][fn][reg] * sc;
            *(f32x4v*)base = v4;
            base[4] = acc[4][fm][fn][reg] * sc;
          }
        }
  }
}

// ---- fat dispatches: 256 thr, 48KB dynamic LDS -> 3 blocks/CU --------------
__global__ __launch_bounds__(256, 3) void fat1_kernel(
    const unsigned short* __restrict__ Xp, const unsigned short* __restrict__ W,
    unsigned short* __restrict__ Hp) {
  extern __shared__ unsigned short sm[];
  int b = blockIdx.x;
  if (b < 2048) {        // l0: 128x128, K=512  (dbuf 32KB)
    gemm_core<1, 128, 128, 512, 1024, 0>(sm, b, Xp, 0, W, Hp, 0, 0, 0.04419417382f);
  } else if (b < 4096) { // l1: P=3, 64x128, K=256  (dbuf 40KB)
    gemm_core<3, 64, 128, 256, 512, 0>(sm, b - 2048, Xp + NL * 512, NL * 256, W + 524288,
                                       Hp + NL * 1024, NL * 512, 0, 0.0625f);
  } else {               // l2: P=5, 64x64, K=128  (dbuf 48KB)
    gemm_core<5, 64, 64, 128, 256, 0>(sm, b - 4096, Xp + NL * 1280, NL * 128, W + 655360,
                                      Hp + NL * 2560, NL * 256, 0, 0.08838834765f);
  }
}

__global__ __launch_bounds__(256, 3) void fat2_kernel(
    const unsigned short* __restrict__ Hp, const unsigned short* __restrict__ W,
    float* __restrict__ out) {
  extern __shared__ unsigned short sm[];
  int b = blockIdx.x;
  if (b < 1024) {        // l0: 128x128, K=1024
    gemm_core<1, 128, 128, 1024, 512, 1>(sm, b, Hp, 0, W + 688128, out, 0, 0, 0.03125f);
  } else if (b < 2048) { // l1: P=3, 64x128, K=512
    gemm_core<3, 64, 128, 512, 256, 1>(sm, b - 1024, Hp + NL * 1024, NL * 512, W + 1212416,
                                       out, 0, 512, 0.04419417382f);
  } else {               // l2: P=5, 64x64, K=256
    gemm_core<5, 64, 64, 256, 128, 1>(sm, b - 2048, Hp + NL * 2560, NL * 256, W + 1343488,
                                      out, 0, 1280, 0.0625f);
  }
}

extern "C" void kernel_launch(void* const* d_in, const int* in_sizes, int n_in,
                              void* d_out, int out_size, void* d_ws, size_t ws_size,
                              hipStream_t stream) {
  const float* x = (const float*)d_in[0];
  const float* w1_0 = (const float*)d_in[1];
  const float* w1_1 = (const float*)d_in[2];
  const float* w1_2 = (const float*)d_in[3];
  const float* w2_0 = (const float*)d_in[4];
  const float* w2_1 = (const float*)d_in[5];
  const float* w2_2 = (const float*)d_in[6];
  float* out = (float*)d_out;

  unsigned short* Xp = (unsigned short*)d_ws;      // N*1920 bf16
  unsigned short* Hp = Xp + NL * 1920;             // N*3840 bf16
  unsigned short* W  = Hp + NL * 3840;             // 1376256 bf16 (all Wt blocks)

  {
    long total = NL * 896 + 1376256;
    prep_kernel<<<dim3((unsigned)((total + 255) / 256)), dim3(256), 0, stream>>>(
        x, w1_0, w1_1, w1_2, w2_0, w2_1, w2_2, Xp, W);
  }

  fat1_kernel<<<6144, 256, 49152, stream>>>(Xp, W, Hp);
  fat2_kernel<<<3072, 256, 49152, stream>>>(Hp, W, out);
}